// Round 11
// baseline (139.330 us; speedup 1.0000x reference)
//
#include <hip/hip_runtime.h>

// SynesthesiaCentralOrchestrator: per-point Karcher mean of 4 unit quaternions,
// 10 fixed iterations. Quaternion float4: .x=w, .y=x, .z=y, .w=z.
//
// R3:  per-block partials instead of single-address atomicAdd.
// R6:  ambient linear-combination update: E = T - d*mu, mu' = c*mu + sc*E.
// R8:  2 independent chains/thread (ILP). Issue/exec-bound.
// R10: float2 SoA packing via __builtin_elementwise_fma: counters show it
//      SCALARIZED (VALUBusy*dur/waves ~= 2.3x packed static count = 1.0x
//      scalar count). -7% was the extra ILP only.
// R11: force VOP3P with inline asm: v_pk_fma_f32 / v_pk_mul_f32 / v_pk_add_f32
//      on "v"-constrained 8-byte v2f operands (even-aligned VGPR pairs).
//      Discriminates: CDNA4 pk-fp32 dual-rate (CDNA2-style, -30%) vs
//      same-rate (neutral -> we are at the fp32 exec roofline).

typedef float v2f __attribute__((ext_vector_type(2)));

#define NPTS (2048 * 2048)
#define NBLK (NPTS / 1024)   // 4096 blocks; ws usage = 16 KB

__device__ __forceinline__ float frcp(float x) { return __builtin_amdgcn_rcpf(x); }
__device__ __forceinline__ float frsq(float x) { return __builtin_amdgcn_rsqf(x); }
__device__ __forceinline__ float fsqrt(float x) { return __builtin_amdgcn_sqrtf(x); }

__device__ __forceinline__ v2f pk_fma(v2f a, v2f b, v2f c) {
    v2f d;
    asm("v_pk_fma_f32 %0, %1, %2, %3" : "=v"(d) : "v"(a), "v"(b), "v"(c));
    return d;
}
__device__ __forceinline__ v2f pk_mul(v2f a, v2f b) {
    v2f d;
    asm("v_pk_mul_f32 %0, %1, %2" : "=v"(d) : "v"(a), "v"(b));
    return d;
}
__device__ __forceinline__ v2f pk_add(v2f a, v2f b) {
    v2f d;
    asm("v_pk_add_f32 %0, %1, %2" : "=v"(d) : "v"(a), "v"(b));
    return d;
}

__device__ __forceinline__ v2f vsplat(float s) { v2f r; r.x = s; r.y = s; return r; }
__device__ __forceinline__ v2f pack(float a, float b) { v2f r; r.x = a; r.y = b; return r; }

__device__ __forceinline__ float4 qnorm_fast(const float4 q) {
    float inv = frsq(fmaf(q.x, q.x, fmaf(q.y, q.y, fmaf(q.z, q.z, q.w * q.w))));
    return make_float4(q.x * inv, q.y * inv, q.z * inv, q.w * inv);
}

// s(w) = 0.25*acos(w)/sqrt(1-w^2) via acos(a) ~= sqrt(1-a)*t(a)  (A&S 4.4.45,
// |err|<=6.8e-5 rad), coefficients pre-scaled by 0.25. Packed over 2 points.
__device__ __forceinline__ v2f log_scale_v(v2f w) {
    v2f a = __builtin_elementwise_min(__builtin_elementwise_abs(w), vsplat(0.9999999f));
    v2f t = pk_fma(a, pk_fma(a, pk_fma(a, vsplat(-0.004682325f), vsplat(0.018565250f)),
                         vsplat(-0.053028600f)), vsplat(0.392682200f));
    v2f opa = pk_add(a, vsplat(1.0f));
    v2f oma = pk_fma(a, vsplat(-1.0f), vsplat(1.0f));
    v2f r1, r2;
    r1.x = frsq(opa.x); r1.y = frsq(opa.y);
    r2.x = frsq(oma.x); r2.y = frsq(oma.y);
    v2f nt = -t;
    v2f u = pk_fma(vsplat(0.785398163f), r2, nt);
    v2f sel = (w >= vsplat(0.0f)) ? t : u;
    return pk_mul(r1, sel);
}

// cos(sqrt(x)), sin(sqrt(x))/sqrt(x) for x = theta^2 in [0, pi^2], packed.
__device__ __forceinline__ v2f sinc_poly_v(v2f x) {
    v2f s = pk_fma(x, vsplat(1.60590438e-10f), vsplat(-2.50521084e-8f));
    s = pk_fma(x, s, vsplat(2.75573192e-6f));
    s = pk_fma(x, s, vsplat(-1.98412698e-4f));
    s = pk_fma(x, s, vsplat(8.33333333e-3f));
    s = pk_fma(x, s, vsplat(-1.66666667e-1f));
    return pk_fma(x, s, vsplat(1.0f));
}
__device__ __forceinline__ v2f cos_poly_v(v2f x) {
    v2f c = pk_fma(x, vsplat(-1.14707456e-11f), vsplat(2.08767570e-9f));
    c = pk_fma(x, c, vsplat(-2.75573192e-7f));
    c = pk_fma(x, c, vsplat(2.48015873e-5f));
    c = pk_fma(x, c, vsplat(-1.38888889e-3f));
    c = pk_fma(x, c, vsplat(4.16666667e-2f));
    c = pk_fma(x, c, vsplat(-0.5f));
    return pk_fma(x, c, vsplat(1.0f));
}

// P[k*4+c]: quaternion k, component c (c0=w). M[c]: current mean. All v2f
// over the chain's two points. Indices static (callers fully unroll).

// Peeled first iteration: M = P0 exactly -> w0 = 1, s0 = 0.25.
__device__ __forceinline__ void chain_peel(const v2f* P, v2f* M) {
    v2f w[4], s[4];
    #pragma unroll
    for (int k = 1; k < 4; ++k)
        w[k] = pk_fma(P[0], P[k*4+0], pk_fma(P[1], P[k*4+1],
                pk_fma(P[2], P[k*4+2], pk_mul(P[3], P[k*4+3]))));
    #pragma unroll
    for (int k = 1; k < 4; ++k) s[k] = log_scale_v(w[k]);
    v2f d = pk_fma(s[1], w[1], pk_fma(s[2], w[2], pk_fma(s[3], w[3], vsplat(0.25f))));
    v2f nd = -d;
    v2f E[4];
    #pragma unroll
    for (int c = 0; c < 4; ++c) {
        v2f T = pk_fma(s[1], P[1*4+c], pk_fma(s[2], P[2*4+c],
                 pk_fma(s[3], P[3*4+c], pk_mul(vsplat(0.25f), P[c]))));
        E[c] = pk_fma(nd, P[c], T);
    }
    v2f x = pk_fma(E[0], E[0], pk_fma(E[1], E[1], pk_fma(E[2], E[2], pk_mul(E[3], E[3]))));
    v2f sc = sinc_poly_v(x), cc = cos_poly_v(x);
    #pragma unroll
    for (int c = 0; c < 4; ++c) M[c] = pk_fma(cc, P[c], pk_mul(sc, E[c]));
}

__device__ __forceinline__ void chain_iter(const v2f* P, v2f* M) {
    v2f w[4], s[4];
    #pragma unroll
    for (int k = 0; k < 4; ++k)
        w[k] = pk_fma(M[0], P[k*4+0], pk_fma(M[1], P[k*4+1],
                pk_fma(M[2], P[k*4+2], pk_mul(M[3], P[k*4+3]))));
    #pragma unroll
    for (int k = 0; k < 4; ++k) s[k] = log_scale_v(w[k]);
    v2f d = pk_fma(s[0], w[0], pk_fma(s[1], w[1], pk_fma(s[2], w[2], pk_mul(s[3], w[3]))));
    v2f nd = -d;
    v2f E[4];
    #pragma unroll
    for (int c = 0; c < 4; ++c) {
        v2f T = pk_fma(s[0], P[c], pk_fma(s[1], P[1*4+c],
                 pk_fma(s[2], P[2*4+c], pk_mul(s[3], P[3*4+c]))));
        E[c] = pk_fma(nd, M[c], T);
    }
    v2f x = pk_fma(E[0], E[0], pk_fma(E[1], E[1], pk_fma(E[2], E[2], pk_mul(E[3], E[3]))));
    v2f sc = sinc_poly_v(x), cc = cos_poly_v(x);
    #pragma unroll
    for (int c = 0; c < 4; ++c) M[c] = pk_fma(cc, M[c], pk_mul(sc, E[c]));
}

__global__ __launch_bounds__(256) void karcher_kernel(
    const float4* __restrict__ aud, const float4* __restrict__ vis,
    const float4* __restrict__ txt, const float4* __restrict__ gen,
    float* __restrict__ out, float* __restrict__ ws)
{
    const int tid = blockIdx.x * 256 + threadIdx.x;
    const int i0  = tid * 4;          // 4 points/thread = 2 packed chains

    v2f P[2][16], M[2][4];

    #pragma unroll
    for (int ch = 0; ch < 2; ++ch) {
        const int b = i0 + 2 * ch;
        float4 qa, qb;
        qa = qnorm_fast(aud[b]); qb = qnorm_fast(aud[b + 1]);
        P[ch][0]  = pack(qa.x, qb.x); P[ch][1]  = pack(qa.y, qb.y);
        P[ch][2]  = pack(qa.z, qb.z); P[ch][3]  = pack(qa.w, qb.w);
        qa = qnorm_fast(vis[b]); qb = qnorm_fast(vis[b + 1]);
        P[ch][4]  = pack(qa.x, qb.x); P[ch][5]  = pack(qa.y, qb.y);
        P[ch][6]  = pack(qa.z, qb.z); P[ch][7]  = pack(qa.w, qb.w);
        qa = qnorm_fast(txt[b]); qb = qnorm_fast(txt[b + 1]);
        P[ch][8]  = pack(qa.x, qb.x); P[ch][9]  = pack(qa.y, qb.y);
        P[ch][10] = pack(qa.z, qb.z); P[ch][11] = pack(qa.w, qb.w);
        qa = qnorm_fast(gen[b]); qb = qnorm_fast(gen[b + 1]);
        P[ch][12] = pack(qa.x, qb.x); P[ch][13] = pack(qa.y, qb.y);
        P[ch][14] = pack(qa.z, qb.z); P[ch][15] = pack(qa.w, qb.w);
    }

    chain_peel(P[0], M[0]);
    chain_peel(P[1], M[1]);

    // Iterations 2..10, rolled (constants hoisted); two independent packed
    // chains inside one loop body for ILP.
    #pragma unroll 1
    for (int it = 0; it < 9; ++it) {
        chain_iter(P[0], M[0]);
        chain_iter(P[1], M[1]);
    }

    float ss = 0.0f;
    #pragma unroll
    for (int ch = 0; ch < 2; ++ch) {
        v2f* m = M[ch];
        // final normalize (reference normalizes the returned barycenter)
        v2f nn = pk_fma(m[0], m[0], pk_fma(m[1], m[1], pk_fma(m[2], m[2], pk_mul(m[3], m[3]))));
        v2f inv; inv.x = frsq(nn.x); inv.y = frsq(nn.y);
        #pragma unroll
        for (int c = 0; c < 4; ++c) m[c] = pk_mul(m[c], inv);

        float4 oa = make_float4(m[0].x, m[1].x, m[2].x, m[3].x);
        float4 ob = make_float4(m[0].y, m[1].y, m[2].y, m[3].y);
        reinterpret_cast<float4*>(out)[i0 + 2 * ch]     = oa;
        reinterpret_cast<float4*>(out)[i0 + 2 * ch + 1] = ob;

        // curvature contribution |m - m/(|m|+1e-12)|^2 (both lanes)
        v2f nn2 = pk_fma(m[0], m[0], pk_fma(m[1], m[1], pk_fma(m[2], m[2], pk_mul(m[3], m[3]))));
        v2f invn; invn.x = frcp(fsqrt(nn2.x) + 1e-12f);
                  invn.y = frcp(fsqrt(nn2.y) + 1e-12f);
        v2f nim = -invn;
        v2f ssv = vsplat(0.0f);
        #pragma unroll
        for (int c = 0; c < 4; ++c) {
            v2f e = pk_fma(nim, m[c], m[c]);
            ssv = pk_fma(e, e, ssv);
        }
        ss += ssv.x + ssv.y;
    }

    // Output 1: eta = angle(det_s)/pi. det_s imag parts are (a*b - a*b) == 0
    // exactly in fp32; real part = |q|^2 > 0  =>  angle == 0 exactly.
    reinterpret_cast<float4*>(out + 4 * NPTS)[tid] = make_float4(0.f, 0.f, 0.f, 0.f);

    // wave(64) shfl reduce -> LDS across the 4 waves -> one plain store/block
    #pragma unroll
    for (int off = 32; off > 0; off >>= 1)
        ss += __shfl_down(ss, off, 64);
    __shared__ float part[4];
    if ((threadIdx.x & 63) == 0) part[threadIdx.x >> 6] = ss;
    __syncthreads();
    if (threadIdx.x == 0)
        ws[blockIdx.x] = part[0] + part[1] + part[2] + part[3];
}

__global__ __launch_bounds__(256) void finish_kernel(
    const float* __restrict__ ws, float* __restrict__ out)
{
    float s = 0.0f;
    #pragma unroll 4
    for (int k = threadIdx.x; k < NBLK; k += 256)
        s += ws[k];
    #pragma unroll
    for (int off = 32; off > 0; off >>= 1)
        s += __shfl_down(s, off, 64);
    __shared__ float part[4];
    if ((threadIdx.x & 63) == 0) part[threadIdx.x >> 6] = s;
    __syncthreads();
    if (threadIdx.x == 0)
        out[5 * NPTS] = 1.0f / (1.0f + sqrtf(part[0] + part[1] + part[2] + part[3]));
}

extern "C" void kernel_launch(void* const* d_in, const int* in_sizes, int n_in,
                              void* d_out, int out_size, void* d_ws, size_t ws_size,
                              hipStream_t stream) {
    const float4* aud = (const float4*)d_in[0];
    const float4* vis = (const float4*)d_in[1];
    const float4* txt = (const float4*)d_in[2];
    const float4* gen = (const float4*)d_in[3];
    float* out = (float*)d_out;
    float* ws = (float*)d_ws;   // NBLK floats, fully overwritten every call

    karcher_kernel<<<NBLK, 256, 0, stream>>>(aud, vis, txt, gen, out, ws);
    finish_kernel<<<1, 256, 0, stream>>>(ws, out);
}